// Round 1
// baseline (1400.454 us; speedup 1.0000x reference)
//
#include <hip/hip_runtime.h>

#define BB 256
#define TT 1024
#define KK 64

// One block per batch item, 512 threads = 8 waves.
// Phase 1 (NO in-loop barriers; each serial chain on its own SIMD):
//   wave0: forward logsumexp recurrence (single-wave; lane j owns state j,
//          reads the full previous vector from LDS as 16 x float4 broadcast,
//          ordered by explicit s_waitcnt lgkmcnt(0))
//   wave1: Viterbi max-only recurrence + delta checkpoint every 32 steps
//   wave2: gold-path score gather
//   waves 3-7: park at the phase barrier
// Phase 2 (all 8 waves): recompute Viterbi per 32-step segment from the
//   checkpoints with the full tie-exact argmax tournament, filling bpl.
//   (max is exactly associative -> phase-2 deltas bit-match phase 1.)
// Then: segment-map composition, boundary walk, per-segment backtrace.
__global__ __launch_bounds__(512) void crf_mega_kernel(
    const float* __restrict__ em, const int* __restrict__ mask,
    const float* __restrict__ trans, const int* __restrict__ tags,
    float* __restrict__ out_dec, float* ll_sum, int* match, int* maskSum) {

  __shared__ __align__(16) float sdf[2][KK];    // forward s (exp domain)
  __shared__ __align__(16) float sdv[2][KK];    // viterbi delta (phase 1)
  __shared__ __align__(16) float ckpt[33][KK];  // delta checkpoints
  __shared__ __align__(16) float psd[8][2][KK]; // per-wave phase-2 delta
  __shared__ unsigned char mrow[TT];
  __shared__ unsigned char bpl[TT][KK];         // backpointers (64 KB)
  __shared__ unsigned char segm[32][KK];
  __shared__ unsigned char bs[40];
  __shared__ int redm[32];

  const int b = blockIdx.x;
  const int tid = threadIdx.x;
  const int wv = tid >> 6;
  const int j = tid & 63;

  const float* emb = em + (size_t)b * TT * KK;
  const int* mb = mask + (size_t)b * TT;
  const int* tgb = tags + (size_t)b * TT;

  for (int t = tid; t < TT; t += 512) mrow[t] = (unsigned char)(mb[t] ? 1 : 0);
  if (wv == 0) sdf[1][j] = emb[j];
  if (wv == 1) { float d0 = emb[j]; sdv[1][j] = d0; ckpt[0][j] = d0; }
  __syncthreads();  // B0

  if (wv == 0) {
    // =========================== FORWARD (wave 0) ===========================
    float E[KK];
#pragma unroll
    for (int r = 0; r < KK; ++r) E[r] = __expf(trans[r * KK + j]);
    float e_own0 = emb[j];
    float e1 = emb[KK + j];
    float ep[4];
#pragma unroll
    for (int k = 0; k < 4; ++k) ep[k] = emb[(size_t)(2 + k) * KK + j];

    float offset;
    {  // ---- t = 1 special: exponentiate raw e0 with global max ----
      asm volatile("s_waitcnt lgkmcnt(0)" ::: "memory");
      const float4* rv = reinterpret_cast<const float4*>(&sdf[1][0]);
      float4 a[16];
#pragma unroll
      for (int k = 0; k < 16; ++k) a[k] = rv[k];
      float m0 = a[0].x;
#pragma unroll
      for (int k = 0; k < 16; ++k)
        m0 = fmaxf(m0, fmaxf(fmaxf(a[k].x, a[k].y), fmaxf(a[k].z, a[k].w)));
      offset = m0;
      float q = 0.f;
#pragma unroll
      for (int k = 0; k < 16; ++k) {
        q += __expf(a[k].x - m0) * E[4*k]
           + __expf(a[k].y - m0) * E[4*k+1]
           + __expf(a[k].z - m0) * E[4*k+2]
           + __expf(a[k].w - m0) * E[4*k+3];
      }
      q *= __expf(e1);
      float sown = __expf(e_own0 - m0);
      q = mrow[1] ? q : sown;
      sdf[0][j] = q;
    }

    auto fwd_body = [&](int t, float e) {
      int p = t & 1, pn = p ^ 1;
      asm volatile("s_waitcnt lgkmcnt(0)" ::: "memory");  // prev write visible
      const float4* sv = reinterpret_cast<const float4*>(&sdf[p][0]);
      float4 a[16];
#pragma unroll
      for (int k = 0; k < 16; ++k) a[k] = sv[k];
      float sown = sdf[p][j];
      float q0 = 0.f, q1 = 0.f, q2 = 0.f, q3 = 0.f;
#pragma unroll
      for (int k = 0; k < 16; k += 4) {
        q0 += a[k+0].x*E[4*k]    + a[k+0].y*E[4*k+1]
            + a[k+0].z*E[4*k+2]  + a[k+0].w*E[4*k+3];
        q1 += a[k+1].x*E[4*k+4]  + a[k+1].y*E[4*k+5]
            + a[k+1].z*E[4*k+6]  + a[k+1].w*E[4*k+7];
        q2 += a[k+2].x*E[4*k+8]  + a[k+2].y*E[4*k+9]
            + a[k+2].z*E[4*k+10] + a[k+2].w*E[4*k+11];
        q3 += a[k+3].x*E[4*k+12] + a[k+3].y*E[4*k+13]
            + a[k+3].z*E[4*k+14] + a[k+3].w*E[4*k+15];
      }
      float q = (q0 + q1) + (q2 + q3);
      q *= __expf(e);
      q = mrow[t] ? q : sown;
      if ((t & 7) == 0) {   // renorm: max of pre-update s (uniform on all lanes)
        float gm = fmaxf(fmaxf(a[0].x, a[0].y), fmaxf(a[0].z, a[0].w));
#pragma unroll
        for (int k = 1; k < 16; ++k)
          gm = fmaxf(gm, fmaxf(fmaxf(a[k].x, a[k].y), fmaxf(a[k].z, a[k].w)));
        q *= __builtin_amdgcn_rcpf(gm);
        offset += __logf(gm);
      }
      sdf[pn][j] = q;
    };

    int tb = 2;
    for (; tb + 3 <= TT - 1; tb += 4) {
#pragma unroll
      for (int k = 0; k < 4; ++k) {
        int t = tb + k;
        float e = ep[k];
        int tpre = t + 4; if (tpre > TT - 1) tpre = TT - 1;
        ep[k] = emb[(size_t)tpre * KK + j];
        fwd_body(t, e);
      }
    }
    for (int t = tb; t <= TT - 1; ++t) fwd_body(t, ep[(t - 2) & 3]);

    asm volatile("s_waitcnt lgkmcnt(0)" ::: "memory");
    float sfin = sdf[0][j];           // final parity 0
#pragma unroll
    for (int off = 1; off <= 32; off <<= 1) sfin += __shfl_xor(sfin, off);
    if (tid == 0) atomicAdd(ll_sum, -(offset + __logf(sfin)));

  } else if (wv == 1) {
    // ====================== VITERBI max-only (wave 1) ======================
    float C[KK];
#pragma unroll
    for (int r = 0; r < KK; ++r) C[r] = trans[r * KK + j];
    float ep[4];
#pragma unroll
    for (int k = 0; k < 4; ++k) ep[k] = emb[(size_t)(1 + k) * KK + j];

    auto vit1_body = [&](int t, float e) {
      int p = t & 1, pn = p ^ 1;
      asm volatile("s_waitcnt lgkmcnt(0)" ::: "memory");
      const float4* dv = reinterpret_cast<const float4*>(&sdv[p][0]);
      float4 a[16];
#pragma unroll
      for (int k = 0; k < 16; ++k) a[k] = dv[k];
      float down = sdv[p][j];
      float mx[16];
#pragma unroll
      for (int k = 0; k < 16; ++k) {
        float v0 = a[k].x + C[4*k];
        float v1 = a[k].y + C[4*k+1];
        float v2 = a[k].z + C[4*k+2];
        float v3 = a[k].w + C[4*k+3];
        mx[k] = fmaxf(fmaxf(v0, v1), fmaxf(v2, v3));
      }
#pragma unroll
      for (int st = 8; st >= 1; st >>= 1) {
#pragma unroll
        for (int k = 0; k < 16; ++k)
          if (k < st) mx[k] = fmaxf(mx[k], mx[k + st]);
      }
      float nd = mrow[t] ? (mx[0] + e) : down;
      sdv[pn][j] = nd;
      if ((t & 31) == 0) ckpt[t >> 5][j] = nd;   // bit-exact checkpoint
    };

    int tb = 1;
    for (; tb + 3 <= TT - 1; tb += 4) {
#pragma unroll
      for (int k = 0; k < 4; ++k) {
        int t = tb + k;
        float e = ep[k];
        int tpre = t + 4; if (tpre > TT - 1) tpre = TT - 1;
        ep[k] = emb[(size_t)tpre * KK + j];
        vit1_body(t, e);
      }
    }
    for (int t = tb; t <= TT - 1; ++t) vit1_body(t, ep[(t - 1) & 3]);

  } else if (wv == 2) {
    // ========================= PATH SCORE (wave 2) =========================
    float acc = 0.f;
    int cnt = 0;
    for (int t = j; t < TT; t += 64) {
      if (mb[t]) {
        int tg = tgb[t];
        acc += emb[(size_t)t * KK + tg];
        cnt += 1;
        if (t >= 1) acc += trans[tgb[t - 1] * KK + tg];
      }
    }
#pragma unroll
    for (int off = 1; off <= 32; off <<= 1) {
      acc += __shfl_xor(acc, off);
      cnt += __shfl_xor(cnt, off);
    }
    if (j == 0) { atomicAdd(ll_sum, acc); atomicAdd(maskSum, cnt); }
  }
  // waves 3-7 fall through and park at B1.

  asm volatile("" ::: "memory");   // keep C2 loads from hoisting above roles
  float C2[KK];
#pragma unroll
  for (int r = 0; r < KK; ++r) C2[r] = trans[r * KK + j];
  __syncthreads();  // B1 — phase boundary

  // ============ PHASE 2: per-segment argmax recompute (8 waves) ============
#pragma unroll 1
  for (int kk = 0; kk < 4; ++kk) {
    int s = wv + 8 * kk;
    int tStart = 32 * s + 1;
    int tEnd = (s == 31) ? (TT - 1) : (32 * s + 32);
    psd[wv][0][j] = ckpt[s][j];
    int cur = 0;
    float e_nx = emb[(size_t)tStart * KK + j];
#pragma unroll 1
    for (int t = tStart; t <= tEnd; ++t) {
      float e = e_nx;
      if (t < tEnd) e_nx = emb[(size_t)(t + 1) * KK + j];
      asm volatile("s_waitcnt lgkmcnt(0)" ::: "memory");
      const float4* dv = reinterpret_cast<const float4*>(&psd[wv][cur][0]);
      float4 a[16];
#pragma unroll
      for (int k = 0; k < 16; ++k) a[k] = dv[k];
      float down = psd[wv][cur][j];
      // tie-exact tournament: strict >, lower index wins (matches argmax-first)
      float tv[32]; int ti[32];
#pragma unroll
      for (int k = 0; k < 16; ++k) {
        float v0 = a[k].x + C2[4*k];
        float v1 = a[k].y + C2[4*k+1];
        float v2 = a[k].z + C2[4*k+2];
        float v3 = a[k].w + C2[4*k+3];
        bool t0 = v1 > v0;
        tv[2*k]   = t0 ? v1 : v0;
        ti[2*k]   = t0 ? 4*k+1 : 4*k;
        bool t1 = v3 > v2;
        tv[2*k+1] = t1 ? v3 : v2;
        ti[2*k+1] = t1 ? 4*k+3 : 4*k+2;
      }
#pragma unroll
      for (int st = 16; st >= 1; st >>= 1) {
#pragma unroll
        for (int k = 0; k < 32; ++k)
          if (k < st) {
            bool tk = tv[k + st] > tv[k];
            tv[k] = tk ? tv[k + st] : tv[k];
            ti[k] = tk ? ti[k + st] : ti[k];
          }
      }
      int m = mrow[t];
      float nd = m ? (tv[0] + e) : down;
      int bp = m ? ti[0] : j;
      bpl[t][j] = (unsigned char)bp;
      psd[wv][cur ^ 1][j] = nd;
      cur ^= 1;
    }
  }
  __syncthreads();  // B2

  // ---- compose 32-step segment maps (4 chains per thread, ILP) ----
  {
    int j0 = tid & 63;
    int s0 = tid >> 6;     // 0..7
    int xs[4]; int tS[4], tE[4];
#pragma unroll
    for (int kk = 0; kk < 4; ++kk) {
      int s = s0 + 8 * kk;
      xs[kk] = j0;
      tS[kk] = 32 * s + 1;
      tE[kk] = (s == 31) ? (TT - 1) : (32 * s + 32);
    }
    for (int q = 0; q < 32; ++q) {
#pragma unroll
      for (int kk = 0; kk < 4; ++kk) {
        int t = tE[kk] - q;
        if (t >= tS[kk]) xs[kk] = bpl[t][xs[kk]];
      }
    }
#pragma unroll
    for (int kk = 0; kk < 4; ++kk) segm[s0 + 8 * kk][j0] = (unsigned char)xs[kk];
  }
  __syncthreads();  // B3

  if (tid == 0) {   // last_tag argmax (final parity 0) + boundary walk
    float bd = sdv[0][0];
    int lt = 0;
    for (int i = 1; i < KK; ++i) {
      float v2 = sdv[0][i];
      if (v2 > bd) { bd = v2; lt = i; }
    }
    bs[32] = (unsigned char)lt;
    for (int s = 31; s >= 0; --s) bs[s] = segm[s][bs[s + 1]];
  }
  __syncthreads();  // B4

  if (tid < 32) {   // per-segment backtrace
    int s = tid;
    int x = bs[s + 1];
    int cnt = 0;
    int tEnd = (s == 31) ? (TT - 1) : (32 * s + 32);
    if (s == 31) {
      int m = mrow[TT - 1];
      out_dec[(size_t)b * TT + TT - 1] = (float)(m ? x : 0);
      cnt += (m && x == tgb[TT - 1]);
    }
    for (int t = tEnd; t >= 32 * s + 1; --t) {
      x = bpl[t][x];
      int m2 = mrow[t - 1];
      out_dec[(size_t)b * TT + t - 1] = (float)(m2 ? x : 0);
      cnt += (m2 && x == tgb[t - 1]);
    }
    redm[s] = cnt;
  }
  __syncthreads();  // B5
  if (tid == 0) {
    int c = 0;
    for (int s = 0; s < 32; ++s) c += redm[s];
    atomicAdd(match, c);
  }
}

__global__ void finalize_kernel(const float* ll_sum, const int* match,
                                const int* maskSum, float* d_out) {
  d_out[0] = -(*ll_sum) / (float)BB;
  d_out[1 + BB * TT] = (float)(*match) / (float)(*maskSum);
}

extern "C" void kernel_launch(void* const* d_in, const int* in_sizes, int n_in,
                              void* d_out, int out_size, void* d_ws, size_t ws_size,
                              hipStream_t stream) {
  const float* em = (const float*)d_in[0];
  const int* tags = (const int*)d_in[1];
  const int* mask = (const int*)d_in[2];       // bool -> int32 on device
  const float* trans = (const float*)d_in[3];
  float* out = (float*)d_out;

  float* ll_sum = (float*)d_ws;
  int* match = (int*)((char*)d_ws + 4);
  int* maskSum = (int*)((char*)d_ws + 8);

  hipMemsetAsync(d_ws, 0, 12, stream);
  crf_mega_kernel<<<BB, 512, 0, stream>>>(em, mask, trans, tags, out + 1,
                                          ll_sum, match, maskSum);
  finalize_kernel<<<1, 1, 0, stream>>>(ll_sum, match, maskSum, out);
}

// Round 2
// 631.716 us; speedup vs baseline: 2.2169x; 2.2169x over previous
//
#include <hip/hip_runtime.h>

#define BB 256
#define TT 1024
#define KK 64

// One block per batch item, 512 threads = 8 waves.
// Chains are SINGLE-WAVE, all-register: lane j owns state j; the all-to-all
// matvec/max uses v_readlane broadcasts (no LDS, no barriers, no waitcnt).
//   wave0: forward (exp-domain, renorm every 8 steps)
//   wave1: Viterbi max-only + delta checkpoint every 32 steps (fmax is exactly
//          associative -> checkpoints bit-match a fused run)
//   wave2: gold-path score
//   waves 3-7: park at the phase barrier
// Phase B (all 8 waves): recompute 32-step segments from checkpoints with the
// tie-exact argmax tournament (strict >, lower index wins), filling bpl.
// Then: segment-map composition, boundary walk, per-segment backtrace.
__device__ __forceinline__ float rlane(float x, int i) {
  return __int_as_float(__builtin_amdgcn_readlane(__float_as_int(x), i));
}

__device__ __forceinline__ float wavemax(float v) {
#pragma unroll
  for (int off = 1; off <= 32; off <<= 1) v = fmaxf(v, __shfl_xor(v, off));
  return v;
}

__global__ __launch_bounds__(512, 2) void crf_mega_kernel(
    const float* __restrict__ em, const int* __restrict__ mask,
    const float* __restrict__ trans, const int* __restrict__ tags,
    float* __restrict__ out_dec, float* ll_sum, int* match, int* maskSum) {

  __shared__ __align__(16) float ckpt[33][KK];  // delta checkpoints (+final in [32])
  __shared__ unsigned char mrow[TT];
  __shared__ unsigned char bpl[TT][KK];         // backpointers (64 KB)
  __shared__ unsigned char segm[32][KK];
  __shared__ unsigned char bs[40];
  __shared__ int redm[32];

  const int b = blockIdx.x;
  const int tid = threadIdx.x;
  const int wv = tid >> 6;
  const int j = tid & 63;

  const float* emb = em + (size_t)b * TT * KK;
  const int* mb = mask + (size_t)b * TT;
  const int* tgb = tags + (size_t)b * TT;

  for (int t = tid; t < TT; t += 512) mrow[t] = (unsigned char)(mb[t] ? 1 : 0);
  __syncthreads();  // B0

  if (wv == 0) {
    // =========================== FORWARD (wave 0) ===========================
    float E[KK];
#pragma unroll
    for (int r = 0; r < KK; ++r) E[r] = __expf(trans[r * KK + j]);
    float raw = emb[j];
    float x, offset;
    {  // ---- t = 1 special: exponentiate raw e0 with global max ----
      float m0 = wavemax(raw);
      offset = m0;
      float s = __expf(raw - m0);
      float q0 = 0.f, q1 = 0.f, q2 = 0.f, q3 = 0.f;
#pragma unroll
      for (int i = 0; i < KK; i += 4) {
        q0 += rlane(s, i)     * E[i];
        q1 += rlane(s, i + 1) * E[i + 1];
        q2 += rlane(s, i + 2) * E[i + 2];
        q3 += rlane(s, i + 3) * E[i + 3];
      }
      float q = (q0 + q1) + (q2 + q3);
      q *= __expf(emb[KK + j]);
      x = mrow[1] ? q : s;
    }
    float ep[4];   // emission factors, pre-exponentiated at prefetch time
#pragma unroll
    for (int k = 0; k < 4; ++k) ep[k] = __expf(emb[(size_t)(2 + k) * KK + j]);

    auto fwd_body = [&](int t, float e) {
      float q0 = 0.f, q1 = 0.f, q2 = 0.f, q3 = 0.f;
#pragma unroll
      for (int i = 0; i < KK; i += 4) {
        q0 += rlane(x, i)     * E[i];
        q1 += rlane(x, i + 1) * E[i + 1];
        q2 += rlane(x, i + 2) * E[i + 2];
        q3 += rlane(x, i + 3) * E[i + 3];
      }
      float q = (q0 + q1) + (q2 + q3);
      q *= e;
      q = mrow[t] ? q : x;
      if ((t & 7) == 0) {   // renorm by max of PRE-update s (wave-uniform)
        float gm = wavemax(x);
        q *= __builtin_amdgcn_rcpf(gm);
        offset += __logf(gm);
      }
      x = q;
    };

    int tb = 2;
    for (; tb + 3 <= TT - 1; tb += 4) {
#pragma unroll
      for (int k = 0; k < 4; ++k) {
        int t = tb + k;
        float e = ep[k];
        int tpre = t + 4; if (tpre > TT - 1) tpre = TT - 1;
        ep[k] = __expf(emb[(size_t)tpre * KK + j]);
        fwd_body(t, e);
      }
    }
    for (int t = tb; t <= TT - 1; ++t) fwd_body(t, ep[(t - 2) & 3]);

    float ssum = x;
#pragma unroll
    for (int off = 1; off <= 32; off <<= 1) ssum += __shfl_xor(ssum, off);
    if (tid == 0) atomicAdd(ll_sum, -(offset + __logf(ssum)));

  } else if (wv == 1) {
    // ====================== VITERBI max-only (wave 1) ======================
    float C[KK];
#pragma unroll
    for (int r = 0; r < KK; ++r) C[r] = trans[r * KK + j];
    float x = emb[j];
    ckpt[0][j] = x;
    float ep[4];
#pragma unroll
    for (int k = 0; k < 4; ++k) ep[k] = emb[(size_t)(1 + k) * KK + j];

    auto vit_body = [&](int t, float e) {
      float best;
#pragma unroll
      for (int g = 0; g < 8; ++g) {
        int o = 8 * g;
        float v0 = rlane(x, o + 0) + C[o + 0];
        float v1 = rlane(x, o + 1) + C[o + 1];
        float v2 = rlane(x, o + 2) + C[o + 2];
        float v3 = rlane(x, o + 3) + C[o + 3];
        float v4 = rlane(x, o + 4) + C[o + 4];
        float v5 = rlane(x, o + 5) + C[o + 5];
        float v6 = rlane(x, o + 6) + C[o + 6];
        float v7 = rlane(x, o + 7) + C[o + 7];
        float m = fmaxf(fmaxf(fmaxf(v0, v1), fmaxf(v2, v3)),
                        fmaxf(fmaxf(v4, v5), fmaxf(v6, v7)));
        best = (g == 0) ? m : fmaxf(best, m);
      }
      float nd = mrow[t] ? (best + e) : x;
      if ((t & 31) == 0) ckpt[t >> 5][j] = nd;   // bit-exact checkpoint
      x = nd;
    };

    int tb = 1;
    for (; tb + 3 <= TT - 1; tb += 4) {
#pragma unroll
      for (int k = 0; k < 4; ++k) {
        int t = tb + k;
        float e = ep[k];
        int tpre = t + 4; if (tpre > TT - 1) tpre = TT - 1;
        ep[k] = emb[(size_t)tpre * KK + j];
        vit_body(t, e);
      }
    }
    for (int t = tb; t <= TT - 1; ++t) vit_body(t, ep[(t - 1) & 3]);

    ckpt[32][j] = x;   // final delta for last-tag argmax

  } else if (wv == 2) {
    // ========================= PATH SCORE (wave 2) =========================
    float acc = 0.f;
    int cnt = 0;
    for (int t = j; t < TT; t += 64) {
      if (mb[t]) {
        int tg = tgb[t];
        acc += emb[(size_t)t * KK + tg];
        cnt += 1;
        if (t >= 1) acc += trans[tgb[t - 1] * KK + tg];
      }
    }
#pragma unroll
    for (int off = 1; off <= 32; off <<= 1) {
      acc += __shfl_xor(acc, off);
      cnt += __shfl_xor(cnt, off);
    }
    if (j == 0) { atomicAdd(ll_sum, acc); atomicAdd(maskSum, cnt); }
  }
  // waves 3-7 fall through.

  float C2[KK];
#pragma unroll
  for (int r = 0; r < KK; ++r) C2[r] = trans[r * KK + j];
  __syncthreads();  // B1 — phase boundary

  // ====== PHASE B: per-segment argmax recompute (8 waves x 4 segments) ======
#pragma unroll 1
  for (int kk = 0; kk < 4; ++kk) {
    int s = wv + 8 * kk;
    int tS = 32 * s + 1;
    int tE = (s == 31) ? (TT - 1) : (32 * s + 32);
    float x2 = ckpt[s][j];
    float e_nx = emb[(size_t)tS * KK + j];
#pragma unroll 1
    for (int t = tS; t <= tE; ++t) {
      float e = e_nx;
      if (t < tE) e_nx = emb[(size_t)(t + 1) * KK + j];
      // tie-exact grouped tournament: strict >, lower index wins everywhere
      float bv; int bi;
#pragma unroll
      for (int g = 0; g < 8; ++g) {
        int o = 8 * g;
        float v0 = rlane(x2, o + 0) + C2[o + 0];
        float v1 = rlane(x2, o + 1) + C2[o + 1];
        float v2 = rlane(x2, o + 2) + C2[o + 2];
        float v3 = rlane(x2, o + 3) + C2[o + 3];
        float v4 = rlane(x2, o + 4) + C2[o + 4];
        float v5 = rlane(x2, o + 5) + C2[o + 5];
        float v6 = rlane(x2, o + 6) + C2[o + 6];
        float v7 = rlane(x2, o + 7) + C2[o + 7];
        bool c0 = v1 > v0; float a0 = c0 ? v1 : v0; int i0 = c0 ? o + 1 : o + 0;
        bool c1 = v3 > v2; float a1 = c1 ? v3 : v2; int i1 = c1 ? o + 3 : o + 2;
        bool c2 = v5 > v4; float a2 = c2 ? v5 : v4; int i2 = c2 ? o + 5 : o + 4;
        bool c3 = v7 > v6; float a3 = c3 ? v7 : v6; int i3 = c3 ? o + 7 : o + 6;
        bool d0 = a1 > a0; float b0 = d0 ? a1 : a0; int k0 = d0 ? i1 : i0;
        bool d1 = a3 > a2; float b1 = d1 ? a3 : a2; int k1 = d1 ? i3 : i2;
        bool f0 = b1 > b0; float gv = f0 ? b1 : b0; int gi = f0 ? k1 : k0;
        if (g == 0) { bv = gv; bi = gi; }
        else { bool tk = gv > bv; bv = tk ? gv : bv; bi = tk ? gi : bi; }
      }
      int m = mrow[t];
      float nd = m ? (bv + e) : x2;
      int bp = m ? bi : j;
      bpl[t][j] = (unsigned char)bp;
      x2 = nd;
    }
  }
  __syncthreads();  // B2

  // ---- compose 32-step segment maps (4 chains per thread, ILP) ----
  {
    int j0 = tid & 63;
    int s0 = tid >> 6;     // 0..7
    int xs[4]; int tS[4], tE[4];
#pragma unroll
    for (int kk = 0; kk < 4; ++kk) {
      int s = s0 + 8 * kk;
      xs[kk] = j0;
      tS[kk] = 32 * s + 1;
      tE[kk] = (s == 31) ? (TT - 1) : (32 * s + 32);
    }
    for (int q = 0; q < 32; ++q) {
#pragma unroll
      for (int kk = 0; kk < 4; ++kk) {
        int t = tE[kk] - q;
        if (t >= tS[kk]) xs[kk] = bpl[t][xs[kk]];
      }
    }
#pragma unroll
    for (int kk = 0; kk < 4; ++kk) segm[s0 + 8 * kk][j0] = (unsigned char)xs[kk];
  }
  __syncthreads();  // B3

  if (tid == 0) {   // last_tag argmax (strict >, first max) + boundary walk
    float bd = ckpt[32][0];
    int lt = 0;
    for (int i = 1; i < KK; ++i) {
      float v2 = ckpt[32][i];
      if (v2 > bd) { bd = v2; lt = i; }
    }
    bs[32] = (unsigned char)lt;
    for (int s = 31; s >= 0; --s) bs[s] = segm[s][bs[s + 1]];
  }
  __syncthreads();  // B4

  if (tid < 32) {   // per-segment backtrace
    int s = tid;
    int x = bs[s + 1];
    int cnt = 0;
    int tEnd = (s == 31) ? (TT - 1) : (32 * s + 32);
    if (s == 31) {
      int m = mrow[TT - 1];
      out_dec[(size_t)b * TT + TT - 1] = (float)(m ? x : 0);
      cnt += (m && x == tgb[TT - 1]);
    }
    for (int t = tEnd; t >= 32 * s + 1; --t) {
      x = bpl[t][x];
      int m2 = mrow[t - 1];
      out_dec[(size_t)b * TT + t - 1] = (float)(m2 ? x : 0);
      cnt += (m2 && x == tgb[t - 1]);
    }
    redm[s] = cnt;
  }
  __syncthreads();  // B5
  if (tid == 0) {
    int c = 0;
    for (int s = 0; s < 32; ++s) c += redm[s];
    atomicAdd(match, c);
  }
}

__global__ void finalize_kernel(const float* ll_sum, const int* match,
                                const int* maskSum, float* d_out) {
  d_out[0] = -(*ll_sum) / (float)BB;
  d_out[1 + BB * TT] = (float)(*match) / (float)(*maskSum);
}

extern "C" void kernel_launch(void* const* d_in, const int* in_sizes, int n_in,
                              void* d_out, int out_size, void* d_ws, size_t ws_size,
                              hipStream_t stream) {
  const float* em = (const float*)d_in[0];
  const int* tags = (const int*)d_in[1];
  const int* mask = (const int*)d_in[2];       // bool -> int32 on device
  const float* trans = (const float*)d_in[3];
  float* out = (float*)d_out;

  float* ll_sum = (float*)d_ws;
  int* match = (int*)((char*)d_ws + 4);
  int* maskSum = (int*)((char*)d_ws + 8);

  hipMemsetAsync(d_ws, 0, 12, stream);
  crf_mega_kernel<<<BB, 512, 0, stream>>>(em, mask, trans, tags, out + 1,
                                          ll_sum, match, maskSum);
  finalize_kernel<<<1, 1, 0, stream>>>(ll_sum, match, maskSum, out);
}

// Round 3
// 619.313 us; speedup vs baseline: 2.2613x; 1.0200x over previous
//
#include <hip/hip_runtime.h>

#define BB 256
#define TT 1024
#define KK 64

// One block per batch item, 512 threads = 8 waves.
// Chains are SINGLE-WAVE, all-register: lane j owns state j; the all-to-all
// matvec/max uses v_readlane broadcasts (no LDS, no barriers, no waitcnt).
//   wave0: forward (exp-domain, renorm every 8 steps)  -- needs E[64] in VGPRs
//   wave1: Viterbi max-only + delta checkpoint every 32 steps -- needs C[64]
//   wave2: gold-path score
//   waves 3-7: park at the phase barrier
// Phase B (all 8 waves): recompute 32-step segments from checkpoints with the
// tie-exact argmax tournament (strict >, lower index wins), filling bpl.
// Then: segment-map composition, boundary walk, per-segment backtrace.
//
// Register budget is the whole game: amdgpu_waves_per_eu(1,2) gives the
// allocator a 256-VGPR budget, and the LDS pad forces 1 block/CU (which is
// all we ever use: grid=256 on 256 CUs) so that budget is real.
__device__ __forceinline__ float rlane(float x, int i) {
  return __int_as_float(__builtin_amdgcn_readlane(__float_as_int(x), i));
}

__device__ __forceinline__ float wavemax(float v) {
#pragma unroll
  for (int off = 1; off <= 32; off <<= 1) v = fmaxf(v, __shfl_xor(v, off));
  return v;
}

__global__ __launch_bounds__(512)
__attribute__((amdgpu_waves_per_eu(1, 2)))
void crf_mega_kernel(
    const float* __restrict__ em, const int* __restrict__ mask,
    const float* __restrict__ trans, const int* __restrict__ tags,
    float* __restrict__ out_dec, float* ll_sum, int* match, int* maskSum) {

  __shared__ __align__(16) float ckpt[33][KK];  // delta checkpoints (+final in [32])
  __shared__ unsigned char mrow[TT];
  __shared__ unsigned char bpl[TT][KK];         // backpointers (64 KB)
  __shared__ unsigned char segm[32][KK];
  __shared__ unsigned char bs[40];
  __shared__ int redm[32];
  __shared__ float lds_pad[2200];               // occupancy shaping: 1 block/CU

  const int b = blockIdx.x;
  const int tid = threadIdx.x;
  const int wv = tid >> 6;
  const int j = tid & 63;

  if (b == (int)0x7FFFFFF0) lds_pad[tid] = 0.f;   // never true; keeps pad live

  const float* emb = em + (size_t)b * TT * KK;
  const int* mb = mask + (size_t)b * TT;
  const int* tgb = tags + (size_t)b * TT;

  for (int t = tid; t < TT; t += 512) mrow[t] = (unsigned char)(mb[t] ? 1 : 0);
  __syncthreads();  // B0

  if (wv == 0) {
    // =========================== FORWARD (wave 0) ===========================
    float E[KK];
#pragma unroll
    for (int r = 0; r < KK; ++r) E[r] = __expf(trans[r * KK + j]);
    float raw = emb[j];
    float x, offset;
    {  // ---- t = 1 special: exponentiate raw e0 with global max ----
      float m0 = wavemax(raw);
      offset = m0;
      float s = __expf(raw - m0);
      float q0 = 0.f, q1 = 0.f, q2 = 0.f, q3 = 0.f;
#pragma unroll
      for (int i = 0; i < KK; i += 4) {
        q0 += rlane(s, i)     * E[i];
        q1 += rlane(s, i + 1) * E[i + 1];
        q2 += rlane(s, i + 2) * E[i + 2];
        q3 += rlane(s, i + 3) * E[i + 3];
      }
      float q = (q0 + q1) + (q2 + q3);
      q *= __expf(emb[KK + j]);
      x = mrow[1] ? q : s;
    }
    float ep[4];   // emission factors, pre-exponentiated at prefetch time
#pragma unroll
    for (int k = 0; k < 4; ++k) ep[k] = __expf(emb[(size_t)(2 + k) * KK + j]);

    auto fwd_body = [&](int t, float e) {
      float q0 = 0.f, q1 = 0.f, q2 = 0.f, q3 = 0.f;
#pragma unroll
      for (int i = 0; i < KK; i += 4) {
        q0 += rlane(x, i)     * E[i];
        q1 += rlane(x, i + 1) * E[i + 1];
        q2 += rlane(x, i + 2) * E[i + 2];
        q3 += rlane(x, i + 3) * E[i + 3];
      }
      float q = (q0 + q1) + (q2 + q3);
      q *= e;
      q = mrow[t] ? q : x;
      if ((t & 7) == 0) {   // renorm by max of PRE-update s (wave-uniform)
        float gm = wavemax(x);
        q *= __builtin_amdgcn_rcpf(gm);
        offset += __logf(gm);
      }
      x = q;
    };

    int tb = 2;
    for (; tb + 3 <= TT - 1; tb += 4) {
#pragma unroll
      for (int k = 0; k < 4; ++k) {
        int t = tb + k;
        float e = ep[k];
        int tpre = t + 4; if (tpre > TT - 1) tpre = TT - 1;
        ep[k] = __expf(emb[(size_t)tpre * KK + j]);
        fwd_body(t, e);
      }
    }
    for (int t = tb; t <= TT - 1; ++t) fwd_body(t, ep[(t - 2) & 3]);

    float ssum = x;
#pragma unroll
    for (int off = 1; off <= 32; off <<= 1) ssum += __shfl_xor(ssum, off);
    if (tid == 0) atomicAdd(ll_sum, -(offset + __logf(ssum)));

  } else if (wv == 1) {
    // ====================== VITERBI max-only (wave 1) ======================
    float C[KK];
#pragma unroll
    for (int r = 0; r < KK; ++r) C[r] = trans[r * KK + j];
    float x = emb[j];
    ckpt[0][j] = x;
    float ep[4];
#pragma unroll
    for (int k = 0; k < 4; ++k) ep[k] = emb[(size_t)(1 + k) * KK + j];

    auto vit_body = [&](int t, float e) {
      float best;
#pragma unroll
      for (int g = 0; g < 8; ++g) {
        int o = 8 * g;
        float v0 = rlane(x, o + 0) + C[o + 0];
        float v1 = rlane(x, o + 1) + C[o + 1];
        float v2 = rlane(x, o + 2) + C[o + 2];
        float v3 = rlane(x, o + 3) + C[o + 3];
        float v4 = rlane(x, o + 4) + C[o + 4];
        float v5 = rlane(x, o + 5) + C[o + 5];
        float v6 = rlane(x, o + 6) + C[o + 6];
        float v7 = rlane(x, o + 7) + C[o + 7];
        // max3-fusable nests; fmax is exact so tree shape is value-identical
        float w0 = fmaxf(fmaxf(v0, v1), v2);
        float w1 = fmaxf(fmaxf(v3, v4), v5);
        float w2 = fmaxf(fmaxf(v6, v7), w0);
        float m = fmaxf(w1, w2);
        best = (g == 0) ? m : fmaxf(best, m);
      }
      float nd = mrow[t] ? (best + e) : x;
      if ((t & 31) == 0) ckpt[t >> 5][j] = nd;   // bit-exact checkpoint
      x = nd;
    };

    int tb = 1;
    for (; tb + 3 <= TT - 1; tb += 4) {
#pragma unroll
      for (int k = 0; k < 4; ++k) {
        int t = tb + k;
        float e = ep[k];
        int tpre = t + 4; if (tpre > TT - 1) tpre = TT - 1;
        ep[k] = emb[(size_t)tpre * KK + j];
        vit_body(t, e);
      }
    }
    for (int t = tb; t <= TT - 1; ++t) vit_body(t, ep[(t - 1) & 3]);

    ckpt[32][j] = x;   // final delta for last-tag argmax

  } else if (wv == 2) {
    // ========================= PATH SCORE (wave 2) =========================
    float acc = 0.f;
    int cnt = 0;
    for (int t = j; t < TT; t += 64) {
      if (mb[t]) {
        int tg = tgb[t];
        acc += emb[(size_t)t * KK + tg];
        cnt += 1;
        if (t >= 1) acc += trans[tgb[t - 1] * KK + tg];
      }
    }
#pragma unroll
    for (int off = 1; off <= 32; off <<= 1) {
      acc += __shfl_xor(acc, off);
      cnt += __shfl_xor(cnt, off);
    }
    if (j == 0) { atomicAdd(ll_sum, acc); atomicAdd(maskSum, cnt); }
  }
  // waves 3-7 fall through.

  __syncthreads();  // B1 — phase boundary

  // C2 loaded AFTER B1 so its 64 registers never overlap the chain loops.
  float C2[KK];
#pragma unroll
  for (int r = 0; r < KK; ++r) C2[r] = trans[r * KK + j];

  // ====== PHASE B: per-segment argmax recompute (8 waves x 4 segments) ======
#pragma unroll 1
  for (int kk = 0; kk < 4; ++kk) {
    int s = wv + 8 * kk;
    int tS = 32 * s + 1;
    int tE = (s == 31) ? (TT - 1) : (32 * s + 32);
    float x2 = ckpt[s][j];
    float e_nx = emb[(size_t)tS * KK + j];
#pragma unroll 1
    for (int t = tS; t <= tE; ++t) {
      float e = e_nx;
      if (t < tE) e_nx = emb[(size_t)(t + 1) * KK + j];
      // tie-exact grouped tournament: strict >, lower index wins everywhere
      float bv; int bi;
#pragma unroll
      for (int g = 0; g < 8; ++g) {
        int o = 8 * g;
        float v0 = rlane(x2, o + 0) + C2[o + 0];
        float v1 = rlane(x2, o + 1) + C2[o + 1];
        float v2 = rlane(x2, o + 2) + C2[o + 2];
        float v3 = rlane(x2, o + 3) + C2[o + 3];
        float v4 = rlane(x2, o + 4) + C2[o + 4];
        float v5 = rlane(x2, o + 5) + C2[o + 5];
        float v6 = rlane(x2, o + 6) + C2[o + 6];
        float v7 = rlane(x2, o + 7) + C2[o + 7];
        bool c0 = v1 > v0; float a0 = c0 ? v1 : v0; int i0 = c0 ? o + 1 : o + 0;
        bool c1 = v3 > v2; float a1 = c1 ? v3 : v2; int i1 = c1 ? o + 3 : o + 2;
        bool c2 = v5 > v4; float a2 = c2 ? v5 : v4; int i2 = c2 ? o + 5 : o + 4;
        bool c3 = v7 > v6; float a3 = c3 ? v7 : v6; int i3 = c3 ? o + 7 : o + 6;
        bool d0 = a1 > a0; float b0 = d0 ? a1 : a0; int k0 = d0 ? i1 : i0;
        bool d1 = a3 > a2; float b1 = d1 ? a3 : a2; int k1 = d1 ? i3 : i2;
        bool f0 = b1 > b0; float gv = f0 ? b1 : b0; int gi = f0 ? k1 : k0;
        if (g == 0) { bv = gv; bi = gi; }
        else { bool tk = gv > bv; bv = tk ? gv : bv; bi = tk ? gi : bi; }
      }
      int m = mrow[t];
      float nd = m ? (bv + e) : x2;
      int bp = m ? bi : j;
      bpl[t][j] = (unsigned char)bp;
      x2 = nd;
    }
  }
  __syncthreads();  // B2

  // ---- compose 32-step segment maps (4 chains per thread, ILP) ----
  {
    int j0 = tid & 63;
    int s0 = tid >> 6;     // 0..7
    int xs[4]; int tS[4], tE[4];
#pragma unroll
    for (int kk = 0; kk < 4; ++kk) {
      int s = s0 + 8 * kk;
      xs[kk] = j0;
      tS[kk] = 32 * s + 1;
      tE[kk] = (s == 31) ? (TT - 1) : (32 * s + 32);
    }
    for (int q = 0; q < 32; ++q) {
#pragma unroll
      for (int kk = 0; kk < 4; ++kk) {
        int t = tE[kk] - q;
        if (t >= tS[kk]) xs[kk] = bpl[t][xs[kk]];
      }
    }
#pragma unroll
    for (int kk = 0; kk < 4; ++kk) segm[s0 + 8 * kk][j0] = (unsigned char)xs[kk];
  }
  __syncthreads();  // B3

  if (tid == 0) {   // last_tag argmax (strict >, first max) + boundary walk
    float bd = ckpt[32][0];
    int lt = 0;
    for (int i = 1; i < KK; ++i) {
      float v2 = ckpt[32][i];
      if (v2 > bd) { bd = v2; lt = i; }
    }
    bs[32] = (unsigned char)lt;
    for (int s = 31; s >= 0; --s) bs[s] = segm[s][bs[s + 1]];
  }
  __syncthreads();  // B4

  if (tid < 32) {   // per-segment backtrace
    int s = tid;
    int x = bs[s + 1];
    int cnt = 0;
    int tEnd = (s == 31) ? (TT - 1) : (32 * s + 32);
    if (s == 31) {
      int m = mrow[TT - 1];
      out_dec[(size_t)b * TT + TT - 1] = (float)(m ? x : 0);
      cnt += (m && x == tgb[TT - 1]);
    }
    for (int t = tEnd; t >= 32 * s + 1; --t) {
      x = bpl[t][x];
      int m2 = mrow[t - 1];
      out_dec[(size_t)b * TT + t - 1] = (float)(m2 ? x : 0);
      cnt += (m2 && x == tgb[t - 1]);
    }
    redm[s] = cnt;
  }
  __syncthreads();  // B5
  if (tid == 0) {
    int c = 0;
    for (int s = 0; s < 32; ++s) c += redm[s];
    atomicAdd(match, c);
  }
}

__global__ void finalize_kernel(const float* ll_sum, const int* match,
                                const int* maskSum, float* d_out) {
  d_out[0] = -(*ll_sum) / (float)BB;
  d_out[1 + BB * TT] = (float)(*match) / (float)(*maskSum);
}

extern "C" void kernel_launch(void* const* d_in, const int* in_sizes, int n_in,
                              void* d_out, int out_size, void* d_ws, size_t ws_size,
                              hipStream_t stream) {
  const float* em = (const float*)d_in[0];
  const int* tags = (const int*)d_in[1];
  const int* mask = (const int*)d_in[2];       // bool -> int32 on device
  const float* trans = (const float*)d_in[3];
  float* out = (float*)d_out;

  float* ll_sum = (float*)d_ws;
  int* match = (int*)((char*)d_ws + 4);
  int* maskSum = (int*)((char*)d_ws + 8);

  hipMemsetAsync(d_ws, 0, 12, stream);
  crf_mega_kernel<<<BB, 512, 0, stream>>>(em, mask, trans, tags, out + 1,
                                          ll_sum, match, maskSum);
  finalize_kernel<<<1, 1, 0, stream>>>(ll_sum, match, maskSum, out);
}